// Round 4
// baseline (655.287 us; speedup 1.0000x reference)
//
#include <hip/hip_runtime.h>
#include <hip/hip_bf16.h>
#include <cstdint>

#define NN 100000
#define NE 1600000
#define NC 128

constexpr int SCAN_SEG = 1024;
constexpr int NB = (NN + SCAN_SEG - 1) / SCAN_SEG; // 98

// ---------------- CSR build ----------------

__global__ __launch_bounds__(256) void k_init(int* __restrict__ cnt) {
    int i = blockIdx.x * 256 + threadIdx.x;
    if (i < NN) cnt[i] = 0;
}

// one int atomic per edge; returned old value = within-row slot. 4 edges/thread.
__global__ __launch_bounds__(256) void k_count(const int4* __restrict__ dst4, int* __restrict__ cnt,
                                               int4* __restrict__ slot4) {
    int i = blockIdx.x * 256 + threadIdx.x;
    if (i < NE / 4) {
        int4 d = dst4[i];
        int4 s;
        s.x = atomicAdd(&cnt[d.x], 1);
        s.y = atomicAdd(&cnt[d.y], 1);
        s.z = atomicAdd(&cnt[d.z], 1);
        s.w = atomicAdd(&cnt[d.w], 1);
        slot4[i] = s;
    }
}

// ---------------- exclusive scan of cnt -> rowstart ----------------

__global__ __launch_bounds__(256) void k_scan1(const int* __restrict__ cnt, int* __restrict__ bsum) {
    __shared__ int sdata[256];
    int b = blockIdx.x, t = threadIdx.x;
    int base = b * SCAN_SEG + t * 4;
    int s = 0;
    #pragma unroll
    for (int j = 0; j < 4; ++j) { int idx = base + j; if (idx < NN) s += cnt[idx]; }
    sdata[t] = s; __syncthreads();
    for (int off = 128; off > 0; off >>= 1) {
        if (t < off) sdata[t] += sdata[t + off];
        __syncthreads();
    }
    if (t == 0) bsum[b] = sdata[0];
}

__global__ void k_scan2(int* __restrict__ bsum, int* __restrict__ rowstart) {
    if (threadIdx.x == 0 && blockIdx.x == 0) {
        int run = 0;
        for (int i = 0; i < NB; ++i) { int v = bsum[i]; bsum[i] = run; run += v; }
        rowstart[NN] = run;  // == NE
    }
}

__global__ __launch_bounds__(256) void k_scan3(const int* __restrict__ cnt, const int* __restrict__ bsum,
                                               int* __restrict__ rowstart) {
    __shared__ int sdata[256];
    int b = blockIdx.x, t = threadIdx.x;
    int base = b * SCAN_SEG + t * 4;
    int v[4]; int vsum = 0;
    #pragma unroll
    for (int j = 0; j < 4; ++j) { int idx = base + j; v[j] = (idx < NN) ? cnt[idx] : 0; vsum += v[j]; }
    sdata[t] = vsum; __syncthreads();
    int incl = vsum;
    for (int off = 1; off < 256; off <<= 1) {
        int add = (t >= off) ? sdata[t - off] : 0;
        __syncthreads();
        incl += add;
        sdata[t] = incl;
        __syncthreads();
    }
    int run = bsum[b] + (incl - vsum);
    #pragma unroll
    for (int j = 0; j < 4; ++j) {
        int idx = base + j;
        if (idx < NN) { rowstart[idx] = run; run += v[j]; }
    }
}

// ---------------- CSR fill (no atomics): edat[pos] = {src, bits(w)}. 4 edges/thread. ----------------

__global__ __launch_bounds__(256) void k_fill(const int4* __restrict__ src4, const int4* __restrict__ dst4,
                                              const float4* __restrict__ w4, const int* __restrict__ rowstart,
                                              const int4* __restrict__ slot4, int2* __restrict__ edat) {
    int i = blockIdx.x * 256 + threadIdx.x;
    if (i < NE / 4) {
        int4 s = src4[i]; int4 d = dst4[i]; float4 wv = w4[i]; int4 sl = slot4[i];
        edat[rowstart[d.x] + sl.x] = make_int2(s.x, __float_as_int(wv.x));
        edat[rowstart[d.y] + sl.y] = make_int2(s.y, __float_as_int(wv.y));
        edat[rowstart[d.z] + sl.z] = make_int2(s.z, __float_as_int(wv.z));
        edat[rowstart[d.w] + sl.w] = make_int2(s.w, __float_as_int(wv.w));
    }
}

// ---------------- deg -> dinv (no atomics): deg = 1 + sum_row(w) ----------------

__global__ __launch_bounds__(256) void k_degdinv(const int* __restrict__ rs, const int2* __restrict__ edat,
                                                 float* __restrict__ dinv) {
    int i = blockIdx.x * 256 + threadIdx.x;
    if (i < NN) {
        float dg = 1.0f;  // self-loop weight
        int p1 = rs[i + 1];
        for (int p = rs[i]; p < p1; ++p) dg += __int_as_float(edat[p].y);
        dinv[i] = (dg > 0.0f) ? (1.0f / sqrtf(fmaxf(dg, 1e-12f))) : 0.0f;
    }
}

// ---------------- norm: edat[p].y = bits(dinv[src] * w)  (dinv[dst] applied in k_agg) ----------------

__global__ __launch_bounds__(256) void k_norm(const float* __restrict__ dinv, int2* __restrict__ edat) {
    int p = blockIdx.x * 256 + threadIdx.x;
    if (p < NE) {
        int2 ed = edat[p];
        edat[p].y = __float_as_int(dinv[ed.x] * __int_as_float(ed.y));
    }
}

// ---------------- GEMM: H = X @ W  (X [NN,128] f32, W [128,128] f32) ----------------

__global__ __launch_bounds__(256) void k_gemm(const float* __restrict__ Xg, const float* __restrict__ Wg,
                                              float* __restrict__ Hg) {
    __shared__ float Ws[64][128];  // 32 KB
    __shared__ float Xs[64][64];   // 16 KB

    int t  = threadIdx.x;
    int tx = t & 31;
    int ty = t >> 5;
    int c0 = tx * 4;
    int rowBase = blockIdx.x * 64;

    float4 acc[8];
    #pragma unroll
    for (int r = 0; r < 8; ++r) acc[r] = make_float4(0.f, 0.f, 0.f, 0.f);

    for (int kc = 0; kc < 128; kc += 64) {
        #pragma unroll
        for (int j = 0; j < 8; ++j) {
            int l  = (t + j * 256) * 4;
            int kr = l >> 7;
            int cc = l & 127;
            *(float4*)&Ws[kr][cc] = *(const float4*)&Wg[(kc + kr) * NC + cc];
        }
        #pragma unroll
        for (int j = 0; j < 4; ++j) {
            int l  = (t + j * 256) * 4;
            int rr = l >> 6;
            int kk = l & 63;
            int gr = rowBase + rr; if (gr > NN - 1) gr = NN - 1;
            *(float4*)&Xs[rr][kk] = *(const float4*)&Xg[(size_t)gr * NC + kc + kk];
        }
        __syncthreads();

        #pragma unroll 4
        for (int kk = 0; kk < 64; kk += 4) {
            float4 wv0 = *(const float4*)&Ws[kk + 0][c0];
            float4 wv1 = *(const float4*)&Ws[kk + 1][c0];
            float4 wv2 = *(const float4*)&Ws[kk + 2][c0];
            float4 wv3 = *(const float4*)&Ws[kk + 3][c0];
            #pragma unroll
            for (int r = 0; r < 8; ++r) {
                float4 xv = *(const float4*)&Xs[ty * 8 + r][kk];
                acc[r].x = fmaf(xv.x, wv0.x, acc[r].x); acc[r].y = fmaf(xv.x, wv0.y, acc[r].y);
                acc[r].z = fmaf(xv.x, wv0.z, acc[r].z); acc[r].w = fmaf(xv.x, wv0.w, acc[r].w);
                acc[r].x = fmaf(xv.y, wv1.x, acc[r].x); acc[r].y = fmaf(xv.y, wv1.y, acc[r].y);
                acc[r].z = fmaf(xv.y, wv1.z, acc[r].z); acc[r].w = fmaf(xv.y, wv1.w, acc[r].w);
                acc[r].x = fmaf(xv.z, wv2.x, acc[r].x); acc[r].y = fmaf(xv.z, wv2.y, acc[r].y);
                acc[r].z = fmaf(xv.z, wv2.z, acc[r].z); acc[r].w = fmaf(xv.z, wv2.w, acc[r].w);
                acc[r].x = fmaf(xv.w, wv3.x, acc[r].x); acc[r].y = fmaf(xv.w, wv3.y, acc[r].y);
                acc[r].z = fmaf(xv.w, wv3.z, acc[r].z); acc[r].w = fmaf(xv.w, wv3.w, acc[r].w);
            }
        }
        __syncthreads();
    }

    #pragma unroll
    for (int r = 0; r < 8; ++r) {
        int gr = rowBase + ty * 8 + r;
        if (gr < NN) *(float4*)&Hg[(size_t)gr * NC + c0] = acc[r];
    }
}

// ---------------- aggregation ----------------
// One 64-lane wave per node. 8 edge-groups x 8 lanes; each lane owns 16 channels
// (4x float4). 2-way unrolled edge walk -> up to 16 edges in flight per wave.
// out[d] = dinv[d]*(sum_e nrm'*H[src] + dinv[d]*H[d]) + b

template <int RELU>
__global__ __launch_bounds__(256) void k_agg(const float* __restrict__ H, const int* __restrict__ rs,
                                             const int2* __restrict__ edat,
                                             const float* __restrict__ dinv, const float* __restrict__ bias,
                                             float* __restrict__ out) {
    int wid  = (blockIdx.x * 256 + threadIdx.x) >> 6;
    int lane = threadIdx.x & 63;
    if (wid >= NN) return;
    int node = wid;
    int g  = lane >> 3;   // edge group 0..7
    int cl = lane & 7;    // channel lane: owns channels cl*16 .. cl*16+15

    float di = dinv[node];
    float4 a0 = make_float4(0.f,0.f,0.f,0.f), a1 = a0, a2 = a0, a3 = a0;

    // self-loop contribution (before the final *di): di * H[node]
    if (g == 0) {
        const float4* hp = (const float4*)(H + (size_t)node * NC + cl * 16);
        float4 h0 = hp[0], h1 = hp[1], h2 = hp[2], h3 = hp[3];
        a0.x = h0.x*di; a0.y = h0.y*di; a0.z = h0.z*di; a0.w = h0.w*di;
        a1.x = h1.x*di; a1.y = h1.y*di; a1.z = h1.z*di; a1.w = h1.w*di;
        a2.x = h2.x*di; a2.y = h2.y*di; a2.z = h2.z*di; a2.w = h2.w*di;
        a3.x = h3.x*di; a3.y = h3.y*di; a3.z = h3.z*di; a3.w = h3.w*di;
    }

    int p0 = rs[node], p1 = rs[node + 1];
    int p = p0 + g;
    for (; p + 8 < p1; p += 16) {
        long long r1 = __builtin_nontemporal_load((const long long*)&edat[p]);
        long long r2 = __builtin_nontemporal_load((const long long*)&edat[p + 8]);
        int   s1 = (int)(r1 & 0xffffffffLL);  float nw1 = __int_as_float((int)(r1 >> 32));
        int   s2 = (int)(r2 & 0xffffffffLL);  float nw2 = __int_as_float((int)(r2 >> 32));
        const float4* hp1 = (const float4*)(H + (size_t)s1 * NC + cl * 16);
        const float4* hp2 = (const float4*)(H + (size_t)s2 * NC + cl * 16);
        float4 x0 = hp1[0], x1 = hp1[1], x2 = hp1[2], x3 = hp1[3];
        float4 y0 = hp2[0], y1 = hp2[1], y2 = hp2[2], y3 = hp2[3];
        a0.x = fmaf(nw1,x0.x,a0.x); a0.y = fmaf(nw1,x0.y,a0.y); a0.z = fmaf(nw1,x0.z,a0.z); a0.w = fmaf(nw1,x0.w,a0.w);
        a1.x = fmaf(nw1,x1.x,a1.x); a1.y = fmaf(nw1,x1.y,a1.y); a1.z = fmaf(nw1,x1.z,a1.z); a1.w = fmaf(nw1,x1.w,a1.w);
        a2.x = fmaf(nw1,x2.x,a2.x); a2.y = fmaf(nw1,x2.y,a2.y); a2.z = fmaf(nw1,x2.z,a2.z); a2.w = fmaf(nw1,x2.w,a2.w);
        a3.x = fmaf(nw1,x3.x,a3.x); a3.y = fmaf(nw1,x3.y,a3.y); a3.z = fmaf(nw1,x3.z,a3.z); a3.w = fmaf(nw1,x3.w,a3.w);
        a0.x = fmaf(nw2,y0.x,a0.x); a0.y = fmaf(nw2,y0.y,a0.y); a0.z = fmaf(nw2,y0.z,a0.z); a0.w = fmaf(nw2,y0.w,a0.w);
        a1.x = fmaf(nw2,y1.x,a1.x); a1.y = fmaf(nw2,y1.y,a1.y); a1.z = fmaf(nw2,y1.z,a1.z); a1.w = fmaf(nw2,y1.w,a1.w);
        a2.x = fmaf(nw2,y2.x,a2.x); a2.y = fmaf(nw2,y2.y,a2.y); a2.z = fmaf(nw2,y2.z,a2.z); a2.w = fmaf(nw2,y2.w,a2.w);
        a3.x = fmaf(nw2,y3.x,a3.x); a3.y = fmaf(nw2,y3.y,a3.y); a3.z = fmaf(nw2,y3.z,a3.z); a3.w = fmaf(nw2,y3.w,a3.w);
    }
    if (p < p1) {
        long long r1 = __builtin_nontemporal_load((const long long*)&edat[p]);
        int   s1 = (int)(r1 & 0xffffffffLL);  float nw1 = __int_as_float((int)(r1 >> 32));
        const float4* hp1 = (const float4*)(H + (size_t)s1 * NC + cl * 16);
        float4 x0 = hp1[0], x1 = hp1[1], x2 = hp1[2], x3 = hp1[3];
        a0.x = fmaf(nw1,x0.x,a0.x); a0.y = fmaf(nw1,x0.y,a0.y); a0.z = fmaf(nw1,x0.z,a0.z); a0.w = fmaf(nw1,x0.w,a0.w);
        a1.x = fmaf(nw1,x1.x,a1.x); a1.y = fmaf(nw1,x1.y,a1.y); a1.z = fmaf(nw1,x1.z,a1.z); a1.w = fmaf(nw1,x1.w,a1.w);
        a2.x = fmaf(nw1,x2.x,a2.x); a2.y = fmaf(nw1,x2.y,a2.y); a2.z = fmaf(nw1,x2.z,a2.z); a2.w = fmaf(nw1,x2.w,a2.w);
        a3.x = fmaf(nw1,x3.x,a3.x); a3.y = fmaf(nw1,x3.y,a3.y); a3.z = fmaf(nw1,x3.z,a3.z); a3.w = fmaf(nw1,x3.w,a3.w);
    }

    // combine the 8 edge-groups: sum over lanes {cl, cl+8, ..., cl+56}
    #pragma unroll
    for (int m = 8; m <= 32; m <<= 1) {
        a0.x += __shfl_xor(a0.x, m); a0.y += __shfl_xor(a0.y, m); a0.z += __shfl_xor(a0.z, m); a0.w += __shfl_xor(a0.w, m);
        a1.x += __shfl_xor(a1.x, m); a1.y += __shfl_xor(a1.y, m); a1.z += __shfl_xor(a1.z, m); a1.w += __shfl_xor(a1.w, m);
        a2.x += __shfl_xor(a2.x, m); a2.y += __shfl_xor(a2.y, m); a2.z += __shfl_xor(a2.z, m); a2.w += __shfl_xor(a2.w, m);
        a3.x += __shfl_xor(a3.x, m); a3.y += __shfl_xor(a3.y, m); a3.z += __shfl_xor(a3.z, m); a3.w += __shfl_xor(a3.w, m);
    }

    if (g == 0) {
        const float4* bp = (const float4*)(bias + cl * 16);
        float4 b0 = bp[0], b1 = bp[1], b2 = bp[2], b3 = bp[3];
        a0.x = fmaf(a0.x, di, b0.x); a0.y = fmaf(a0.y, di, b0.y); a0.z = fmaf(a0.z, di, b0.z); a0.w = fmaf(a0.w, di, b0.w);
        a1.x = fmaf(a1.x, di, b1.x); a1.y = fmaf(a1.y, di, b1.y); a1.z = fmaf(a1.z, di, b1.z); a1.w = fmaf(a1.w, di, b1.w);
        a2.x = fmaf(a2.x, di, b2.x); a2.y = fmaf(a2.y, di, b2.y); a2.z = fmaf(a2.z, di, b2.z); a2.w = fmaf(a2.w, di, b2.w);
        a3.x = fmaf(a3.x, di, b3.x); a3.y = fmaf(a3.y, di, b3.y); a3.z = fmaf(a3.z, di, b3.z); a3.w = fmaf(a3.w, di, b3.w);
        if (RELU) {
            a0.x=fmaxf(a0.x,0.f); a0.y=fmaxf(a0.y,0.f); a0.z=fmaxf(a0.z,0.f); a0.w=fmaxf(a0.w,0.f);
            a1.x=fmaxf(a1.x,0.f); a1.y=fmaxf(a1.y,0.f); a1.z=fmaxf(a1.z,0.f); a1.w=fmaxf(a1.w,0.f);
            a2.x=fmaxf(a2.x,0.f); a2.y=fmaxf(a2.y,0.f); a2.z=fmaxf(a2.z,0.f); a2.w=fmaxf(a2.w,0.f);
            a3.x=fmaxf(a3.x,0.f); a3.y=fmaxf(a3.y,0.f); a3.z=fmaxf(a3.z,0.f); a3.w=fmaxf(a3.w,0.f);
        }
        float4* op = (float4*)(out + (size_t)node * NC + cl * 16);
        op[0] = a0; op[1] = a1; op[2] = a2; op[3] = a3;
    }
}

// ---------------- launch ----------------

static inline size_t alignup(size_t x) { return (x + 255) & ~(size_t)255; }

extern "C" void kernel_launch(void* const* d_in, const int* in_sizes, int n_in,
                              void* d_out, int out_size, void* d_ws, size_t ws_size,
                              hipStream_t stream) {
    const float* X  = (const float*)d_in[0];
    const int*   ei = (const int*)d_in[1];          // [2, NE]: row0 = src, row1 = dst
    const float* ew = (const float*)d_in[2];
    const float* W1 = (const float*)d_in[3]; const float* b1 = (const float*)d_in[4];
    const float* W2 = (const float*)d_in[5]; const float* b2 = (const float*)d_in[6];
    const float* W3 = (const float*)d_in[7]; const float* b3 = (const float*)d_in[8];
    float* out = (float*)d_out;

    const int* srcp = ei;
    const int* dstp = ei + NE;

    // workspace carve
    char* w = (char*)d_ws;
    size_t need = 0;
    auto carve = [&](size_t bytes) { char* p = w + need; need += alignup(bytes); return p; };
    float* dinv     = (float*)carve(NN * 4);
    int*   cnt      = (int*)  carve(NN * 4);
    int*   rowstart = (int*)  carve((NN + 1) * 4);
    int*   bsum     = (int*)  carve(NB * 4);
    int*   slot     = (int*)  carve((size_t)NE * 4);
    int2*  edat     = (int2*) carve((size_t)NE * 8);
    float* H        = (float*)carve((size_t)NN * NC * 4);
    float* A        = (float*)carve((size_t)NN * NC * 4);
    if (need > ws_size) return;  // workspace too small -> visible validation failure

    const int gN  = (NN + 255) / 256;
    const int gE  = (NE + 255) / 256;
    const int gE4 = (NE / 4 + 255) / 256;
    const int gGemm = (NN + 63) / 64;
    const int gAgg  = (NN * 64 + 255) / 256;  // one wave per node

    // build normalization + CSR (once; reused by all 3 layers)
    k_init<<<gN, 256, 0, stream>>>(cnt);
    k_count<<<gE4, 256, 0, stream>>>((const int4*)dstp, cnt, (int4*)slot);
    k_scan1<<<NB, 256, 0, stream>>>(cnt, bsum);
    k_scan2<<<1, 64, 0, stream>>>(bsum, rowstart);
    k_scan3<<<NB, 256, 0, stream>>>(cnt, bsum, rowstart);
    k_fill<<<gE4, 256, 0, stream>>>((const int4*)srcp, (const int4*)dstp, (const float4*)ew,
                                    rowstart, (const int4*)slot, edat);
    k_degdinv<<<gN, 256, 0, stream>>>(rowstart, edat, dinv);
    k_norm<<<gE, 256, 0, stream>>>(dinv, edat);

    // layer 1
    k_gemm<<<gGemm, 256, 0, stream>>>(X, W1, H);
    k_agg<1><<<gAgg, 256, 0, stream>>>(H, rowstart, edat, dinv, b1, A);
    // layer 2
    k_gemm<<<gGemm, 256, 0, stream>>>(A, W2, H);
    k_agg<1><<<gAgg, 256, 0, stream>>>(H, rowstart, edat, dinv, b2, A);
    // layer 3
    k_gemm<<<gGemm, 256, 0, stream>>>(A, W3, H);
    k_agg<0><<<gAgg, 256, 0, stream>>>(H, rowstart, edat, dinv, b3, out);
}